// Round 2
// baseline (665.015 us; speedup 1.0000x reference)
//
#include <hip/hip_runtime.h>
#include <stdint.h>

#define HD 1024
#define SEQ 2048
#define NC 32

typedef __bf16 bf16x4 __attribute__((ext_vector_type(4)));
typedef __bf16 bf16x8 __attribute__((ext_vector_type(8)));
typedef float f32x4 __attribute__((ext_vector_type(4)));

__device__ inline unsigned short f2bf(float f) {
  union { float f; unsigned int u; } v; v.f = f;
  unsigned int r = v.u + 0x7fffu + ((v.u >> 16) & 1u);
  return (unsigned short)(r >> 16);
}
__device__ inline unsigned int pk2bf(float a, float b) {
  return (unsigned int)f2bf(a) | ((unsigned int)f2bf(b) << 16);
}
// 8-element bf16 fragment from an 8B-aligned LDS address (two b64 reads)
__device__ inline bf16x8 ld_frag8(const unsigned short* p) {
  bf16x4 lo = *(const bf16x4*)p;
  bf16x4 hi = *(const bf16x4*)(p + 4);
  return __builtin_shufflevector(lo, hi, 0, 1, 2, 3, 4, 5, 6, 7);
}

// ---------------- zero rows s<63 of output (fp32) ----------------
__global__ __launch_bounds__(256) void zero_head_kernel(float* __restrict__ out) {
  int i = (blockIdx.x * 256 + threadIdx.x) * 4;  // over 4*63*1024 = 258048 floats
  int b = i / 64512;
  int r = i - b * 64512;
  *(float4*)(out + (size_t)b * (SEQ * HD) + r) = make_float4(0.f, 0.f, 0.f, 0.f);
}

// ---------------- GEMM: C[M,1024] = A[M,1024] @ W[1024,1024]^T + bias ----------------
// A, W, bias are fp32; C is bf16 (workspace). Converts fp32->bf16 while staging to LDS.
// qremap!=0: A row g -> query row (g&2047)+63 within batch g>>11, zero if (g&2047)>=1985
__global__ __launch_bounds__(256, 2) void gemm_bt_kernel(
    const float* __restrict__ A, const float* __restrict__ W,
    const float* __restrict__ bias, unsigned short* __restrict__ Cout,
    int qremap) {
  __shared__ unsigned short lds_a[128 * 32];
  __shared__ unsigned short lds_b[128 * 32];
  const int t = threadIdx.x;
  const int l = t & 63, w = t >> 6;
  const int wm = w >> 1, wn = w & 1;
  const int lr = l & 15, lq = l >> 4;
  const size_t arow0 = (size_t)blockIdx.y * 128;
  const size_t brow0 = (size_t)blockIdx.x * 128;

  f32x4 acc[4][4];
  for (int i = 0; i < 4; i++)
    for (int j = 0; j < 4; j++) acc[i][j] = (f32x4){0.f, 0.f, 0.f, 0.f};

  for (int kk = 0; kk < 32; ++kk) {
    const int k0 = kk * 32;
    uint4 av[2], bv[2];
    for (int p = 0; p < 2; ++p) {
      int chunk = p * 256 + t;
      int row = chunk >> 2;
      int c8 = (chunk & 3) * 8;
      size_t grow = arow0 + row;
      bool valid = true;
      const float* srcA;
      if (qremap) {
        int bb = (int)(grow >> 11), tt = (int)(grow & 2047);
        valid = tt < 1985;
        srcA = A + ((size_t)(bb << 11) + tt + 63) * HD + k0 + c8;
      } else {
        srcA = A + grow * HD + k0 + c8;
      }
      if (valid) {
        float4 a0 = *(const float4*)srcA;
        float4 a1 = *(const float4*)(srcA + 4);
        av[p] = make_uint4(pk2bf(a0.x, a0.y), pk2bf(a0.z, a0.w),
                           pk2bf(a1.x, a1.y), pk2bf(a1.z, a1.w));
      } else {
        av[p] = make_uint4(0, 0, 0, 0);
      }
      const float* srcB = W + (brow0 + row) * HD + k0 + c8;
      float4 b0 = *(const float4*)srcB;
      float4 b1 = *(const float4*)(srcB + 4);
      bv[p] = make_uint4(pk2bf(b0.x, b0.y), pk2bf(b0.z, b0.w),
                         pk2bf(b1.x, b1.y), pk2bf(b1.z, b1.w));
    }
    __syncthreads();
    for (int p = 0; p < 2; ++p) {
      int chunk = p * 256 + t;
      *(uint4*)(lds_a + chunk * 8) = av[p];
      *(uint4*)(lds_b + chunk * 8) = bv[p];
    }
    __syncthreads();
    bf16x8 af[4], bfr[4];
    for (int mt = 0; mt < 4; ++mt)
      af[mt] = *(const bf16x8*)(lds_a + (wm * 64 + mt * 16 + lr) * 32 + lq * 8);
    for (int nt = 0; nt < 4; ++nt)
      bfr[nt] = *(const bf16x8*)(lds_b + (wn * 64 + nt * 16 + lr) * 32 + lq * 8);
    for (int mt = 0; mt < 4; ++mt)
      for (int nt = 0; nt < 4; ++nt)
        acc[mt][nt] = __builtin_amdgcn_mfma_f32_16x16x32_bf16(af[mt], bfr[nt], acc[mt][nt], 0, 0, 0);
  }

  for (int nt = 0; nt < 4; ++nt) {
    int n = blockIdx.x * 128 + wn * 64 + nt * 16 + lr;
    float bvv = bias[n];
    for (int mt = 0; mt < 4; ++mt) {
      size_t mbase = arow0 + wm * 64 + mt * 16 + lq * 4;
      for (int r = 0; r < 4; ++r)
        Cout[(mbase + r) * HD + n] = f2bf(acc[mt][nt][r] + bvv);
    }
  }
}

// ---------------- fused attention per (b, c, head) ----------------
#define QK_STRIDE 68   // 64 + 4 pad, banks spread, 8B-aligned rows
#define P_STRIDE 260   // P overlay inside k_s
#define VT_STRIDE 132  // V^T tile (half of j-range at a time)

__global__ __launch_bounds__(256, 2) void attn_kernel(
    const unsigned short* __restrict__ Qp, const unsigned short* __restrict__ Kp,
    const unsigned short* __restrict__ Vp, float* __restrict__ out) {
  __shared__ unsigned short q_s[64 * QK_STRIDE];    // 8704 B
  __shared__ unsigned short k_s[256 * QK_STRIDE];   // 34816 B (P overlays: 64 x 260 fits)
  __shared__ unsigned short vt_s[64 * VT_STRIDE];   // 16896 B
  const int t = threadIdx.x;
  const int l = t & 63, w = t >> 6;
  const int lr = l & 15, lq = l >> 4;
  const int bid = blockIdx.x;
  const int head = bid & 15, cc = (bid >> 4) & 31, b = bid >> 9;
  const size_t qrow0 = (size_t)(b * NC + cc) * 64;
  const size_t kvrow0 = (size_t)(b * NC + cc) * 256;
  const int hcol = head * 64;

  // stage q (64x64 bf16)
  for (int p = 0; p < 4; ++p) {
    int chunk = p * 256 + t;
    int row = chunk >> 4, c4 = (chunk & 15) * 4;
    *(uint2*)(q_s + row * QK_STRIDE + c4) = *(const uint2*)(Qp + (qrow0 + row) * HD + hcol + c4);
  }
  // stage k (256x64 bf16)
  for (int p = 0; p < 16; ++p) {
    int chunk = p * 256 + t;
    int row = chunk >> 4, c4 = (chunk & 15) * 4;
    *(uint2*)(k_s + row * QK_STRIDE + c4) = *(const uint2*)(Kp + (kvrow0 + row) * HD + hcol + c4);
  }
  // stage V^T half 0 (j in [0,128))
  for (int p = 0; p < 4; ++p) {
    int chunk = p * 256 + t;
    int j = chunk >> 3, c8 = (chunk & 7) * 8;
    uint4 vv = *(const uint4*)(Vp + (kvrow0 + j) * HD + hcol + c8);
    vt_s[(c8 + 0) * VT_STRIDE + j] = (unsigned short)(vv.x & 0xffff);
    vt_s[(c8 + 1) * VT_STRIDE + j] = (unsigned short)(vv.x >> 16);
    vt_s[(c8 + 2) * VT_STRIDE + j] = (unsigned short)(vv.y & 0xffff);
    vt_s[(c8 + 3) * VT_STRIDE + j] = (unsigned short)(vv.y >> 16);
    vt_s[(c8 + 4) * VT_STRIDE + j] = (unsigned short)(vv.z & 0xffff);
    vt_s[(c8 + 5) * VT_STRIDE + j] = (unsigned short)(vv.z >> 16);
    vt_s[(c8 + 6) * VT_STRIDE + j] = (unsigned short)(vv.w & 0xffff);
    vt_s[(c8 + 7) * VT_STRIDE + j] = (unsigned short)(vv.w >> 16);
  }
  __syncthreads();

  // scores: wave w owns q rows [w*16, w*16+16)
  bf16x8 qa0 = ld_frag8(q_s + (w * 16 + lr) * QK_STRIDE + lq * 8);
  bf16x8 qa1 = ld_frag8(q_s + (w * 16 + lr) * QK_STRIDE + 32 + lq * 8);
  f32x4 sc[16];
  for (int nt = 0; nt < 16; ++nt) {
    bf16x8 kb0 = ld_frag8(k_s + (nt * 16 + lr) * QK_STRIDE + lq * 8);
    bf16x8 kb1 = ld_frag8(k_s + (nt * 16 + lr) * QK_STRIDE + 32 + lq * 8);
    f32x4 a = (f32x4){0.f, 0.f, 0.f, 0.f};
    a = __builtin_amdgcn_mfma_f32_16x16x32_bf16(qa0, kb0, a, 0, 0, 0);
    a = __builtin_amdgcn_mfma_f32_16x16x32_bf16(qa1, kb1, a, 0, 0, 0);
    sc[nt] = a;
  }
  // softmax over 256 cols; this lane's rows are lq*4 + r
  float mrow[4] = {-1e30f, -1e30f, -1e30f, -1e30f};
  for (int nt = 0; nt < 16; ++nt)
    for (int r = 0; r < 4; ++r) mrow[r] = fmaxf(mrow[r], sc[nt][r]);
  for (int off = 1; off < 16; off <<= 1)
    for (int r = 0; r < 4; ++r) mrow[r] = fmaxf(mrow[r], __shfl_xor(mrow[r], off, 16));
  float srow[4] = {0.f, 0.f, 0.f, 0.f};
  const float cexp = 0.18033688011112042f;  // log2(e)/8  (scale 1/sqrt(64))
  for (int nt = 0; nt < 16; ++nt)
    for (int r = 0; r < 4; ++r) {
      float p = exp2f((sc[nt][r] - mrow[r]) * cexp);
      sc[nt][r] = p;
      srow[r] += p;
    }
  for (int off = 1; off < 16; off <<= 1)
    for (int r = 0; r < 4; ++r) srow[r] += __shfl_xor(srow[r], off, 16);

  __syncthreads();  // everyone done reading k_s

  // write P (bf16) into k_s overlay; wave-local rows, no barrier needed before own reads
  for (int nt = 0; nt < 16; ++nt)
    for (int r = 0; r < 4; ++r)
      k_s[(w * 16 + lq * 4 + r) * P_STRIDE + nt * 16 + lr] = f2bf(sc[nt][r]);

  f32x4 o[4];
  for (int i = 0; i < 4; ++i) o[i] = (f32x4){0.f, 0.f, 0.f, 0.f};
  for (int half = 0; half < 2; ++half) {
    if (half == 1) {
      __syncthreads();  // PV half0 reads done
      for (int p = 0; p < 4; ++p) {
        int chunk = p * 256 + t;
        int j = chunk >> 3, c8 = (chunk & 7) * 8;
        uint4 vv = *(const uint4*)(Vp + (kvrow0 + 128 + j) * HD + hcol + c8);
        vt_s[(c8 + 0) * VT_STRIDE + j] = (unsigned short)(vv.x & 0xffff);
        vt_s[(c8 + 1) * VT_STRIDE + j] = (unsigned short)(vv.x >> 16);
        vt_s[(c8 + 2) * VT_STRIDE + j] = (unsigned short)(vv.y & 0xffff);
        vt_s[(c8 + 3) * VT_STRIDE + j] = (unsigned short)(vv.y >> 16);
        vt_s[(c8 + 4) * VT_STRIDE + j] = (unsigned short)(vv.z & 0xffff);
        vt_s[(c8 + 5) * VT_STRIDE + j] = (unsigned short)(vv.z >> 16);
        vt_s[(c8 + 6) * VT_STRIDE + j] = (unsigned short)(vv.w & 0xffff);
        vt_s[(c8 + 7) * VT_STRIDE + j] = (unsigned short)(vv.w >> 16);
      }
      __syncthreads();
    }
    for (int ks = 0; ks < 4; ++ks) {
      bf16x8 pa = ld_frag8(k_s + (w * 16 + lr) * P_STRIDE + half * 128 + ks * 32 + lq * 8);
      for (int nt2 = 0; nt2 < 4; ++nt2) {
        bf16x8 vb = ld_frag8(vt_s + (nt2 * 16 + lr) * VT_STRIDE + ks * 32 + lq * 8);
        o[nt2] = __builtin_amdgcn_mfma_f32_16x16x32_bf16(pa, vb, o[nt2], 0, 0, 0);
      }
    }
  }

  // epilogue: out[b, t+63, head*64 + col] = o / rowsum (fp32), drop t >= 1985
  for (int r = 0; r < 4; ++r) {
    int strip = w * 16 + lq * 4 + r;
    int trow = cc * 64 + strip;
    if (trow < 1985) {
      size_t orow = (size_t)b * SEQ + trow + 63;
      float inv = 1.0f / srow[r];
      for (int nt2 = 0; nt2 < 4; ++nt2)
        out[orow * HD + hcol + nt2 * 16 + lr] = o[nt2][r] * inv;
    }
  }
}

extern "C" void kernel_launch(void* const* d_in, const int* in_sizes, int n_in,
                              void* d_out, int out_size, void* d_ws, size_t ws_size,
                              hipStream_t stream) {
  (void)in_sizes; (void)n_in; (void)out_size; (void)ws_size;
  const float* query = (const float*)d_in[0];
  const float* kv    = (const float*)d_in[1];
  const float* Wq    = (const float*)d_in[2];
  const float* bq    = (const float*)d_in[3];
  const float* Wk    = (const float*)d_in[4];
  const float* bk    = (const float*)d_in[5];
  const float* Wv    = (const float*)d_in[6];
  const float* bv    = (const float*)d_in[7];
  float* out = (float*)d_out;

  unsigned short* Qp = (unsigned short*)d_ws;                 // 8192*1024 bf16
  unsigned short* Kp = Qp + (size_t)8192 * 1024;              // 32768*1024 bf16
  unsigned short* Vp = Kp + (size_t)32768 * 1024;             // 32768*1024 bf16

  zero_head_kernel<<<dim3(252), dim3(256), 0, stream>>>(out);
  gemm_bt_kernel<<<dim3(8, 64), dim3(256), 0, stream>>>(query, Wq, bq, Qp, 1);
  gemm_bt_kernel<<<dim3(8, 256), dim3(256), 0, stream>>>(kv, Wk, bk, Kp, 0);
  gemm_bt_kernel<<<dim3(8, 256), dim3(256), 0, stream>>>(kv, Wv, bv, Vp, 0);
  attn_kernel<<<dim3(2048), dim3(256), 0, stream>>>(Qp, Kp, Vp, out);
}

// Round 3
// 519.640 us; speedup vs baseline: 1.2798x; 1.2798x over previous
//
#include <hip/hip_runtime.h>
#include <stdint.h>

#define HD 1024
#define SEQ 2048
#define NC 32

typedef __bf16 bf16x4 __attribute__((ext_vector_type(4)));
typedef __bf16 bf16x8 __attribute__((ext_vector_type(8)));
typedef float f32x4 __attribute__((ext_vector_type(4)));

__device__ inline unsigned short f2bf(float f) {
  union { float f; unsigned int u; } v; v.f = f;
  unsigned int r = v.u + 0x7fffu + ((v.u >> 16) & 1u);
  return (unsigned short)(r >> 16);
}
__device__ inline unsigned int pk2bf(float a, float b) {
  return (unsigned int)f2bf(a) | ((unsigned int)f2bf(b) << 16);
}
__device__ inline bf16x8 ld_frag8(const unsigned short* p) {
  bf16x4 lo = *(const bf16x4*)p;
  bf16x4 hi = *(const bf16x4*)(p + 4);
  return __builtin_shufflevector(lo, hi, 0, 1, 2, 3, 4, 5, 6, 7);
}
// async 16B global->LDS (wave-uniform base + lane*16; chunk layout is linear so this holds)
__device__ inline void glds16(const unsigned short* g, unsigned short* l) {
  __builtin_amdgcn_global_load_lds(
      (const __attribute__((address_space(1))) unsigned int*)g,
      (__attribute__((address_space(3))) unsigned int*)l, 16, 0, 0);
}

// ---------------- zero rows s<63 of output (fp32) ----------------
__global__ __launch_bounds__(256) void zero_head_kernel(float* __restrict__ out) {
  int i = (blockIdx.x * 256 + threadIdx.x) * 4;
  int b = i / 64512;
  int r = i - b * 64512;
  *(float4*)(out + (size_t)b * (SEQ * HD) + r) = make_float4(0.f, 0.f, 0.f, 0.f);
}

// ---------------- fp32 -> bf16 streaming convert (8 elems/thread) ----------------
__global__ __launch_bounds__(256) void cvt_kernel(const float* __restrict__ in,
                                                  unsigned short* __restrict__ out, int n8) {
  int i = blockIdx.x * 256 + threadIdx.x;
  if (i < n8) {
    float4 a = ((const float4*)in)[(size_t)i * 2];
    float4 b = ((const float4*)in)[(size_t)i * 2 + 1];
    ((uint4*)out)[i] = make_uint4(pk2bf(a.x, a.y), pk2bf(a.z, a.w),
                                  pk2bf(b.x, b.y), pk2bf(b.z, b.w));
  }
}

// ---------------- query remap+pad -> bf16 (8192 x 1024) ----------------
__global__ __launch_bounds__(256) void cvt_q_kernel(const float* __restrict__ q,
                                                    unsigned short* __restrict__ out) {
  int i = blockIdx.x * 256 + threadIdx.x;  // [0, 8192*128)
  int g = i >> 7, c8 = (i & 127) * 8;
  int b = g >> 11, tt = g & 2047;
  uint4 o = make_uint4(0, 0, 0, 0);
  if (tt < 1985) {
    const float* src = q + ((size_t)(b << 11) + tt + 63) * HD + c8;
    float4 a = *(const float4*)src;
    float4 bb = *(const float4*)(src + 4);
    o = make_uint4(pk2bf(a.x, a.y), pk2bf(a.z, a.w), pk2bf(bb.x, bb.y), pk2bf(bb.z, bb.w));
  }
  *(uint4*)(out + (size_t)g * HD + c8) = o;
}

// ---------------- GEMM (bf16 in, glds staging): C[M,1024] = A @ W^T + bias ----------------
// store_vt: write C transposed per (bc,head): Vt[((bc*16+h)*64+d)*256 + j]
__global__ __launch_bounds__(256, 2) void gemm_bf_kernel(
    const unsigned short* __restrict__ A, const unsigned short* __restrict__ W,
    const float* __restrict__ bias, unsigned short* __restrict__ Cout, int store_vt) {
  __shared__ unsigned short lds_a[128 * 32];
  __shared__ unsigned short lds_b[128 * 32];
  const int t = threadIdx.x;
  const int l = t & 63, w = t >> 6;
  const int wm = w >> 1, wn = w & 1;
  const int lr = l & 15, lq = l >> 4;
  const size_t arow0 = (size_t)blockIdx.y * 128;
  const size_t brow0 = (size_t)blockIdx.x * 128;
  const int c0 = t, c1 = 256 + t;
  const unsigned short* a0 = A + (arow0 + (c0 >> 2)) * HD + (c0 & 3) * 8;
  const unsigned short* a1 = A + (arow0 + (c1 >> 2)) * HD + (c1 & 3) * 8;
  const unsigned short* b0 = W + (brow0 + (c0 >> 2)) * HD + (c0 & 3) * 8;
  const unsigned short* b1 = W + (brow0 + (c1 >> 2)) * HD + (c1 & 3) * 8;

  f32x4 acc[4][4];
  for (int i = 0; i < 4; i++)
    for (int j = 0; j < 4; j++) acc[i][j] = (f32x4){0.f, 0.f, 0.f, 0.f};

  for (int kk = 0; kk < 32; ++kk) {
    const int k0 = kk * 32;
    __syncthreads();
    glds16(a0 + k0, lds_a + c0 * 8);
    glds16(a1 + k0, lds_a + c1 * 8);
    glds16(b0 + k0, lds_b + c0 * 8);
    glds16(b1 + k0, lds_b + c1 * 8);
    __syncthreads();
    bf16x8 af[4], bfr[4];
    for (int mt = 0; mt < 4; ++mt)
      af[mt] = *(const bf16x8*)(lds_a + (wm * 64 + mt * 16 + lr) * 32 + lq * 8);
    for (int nt = 0; nt < 4; ++nt)
      bfr[nt] = *(const bf16x8*)(lds_b + (wn * 64 + nt * 16 + lr) * 32 + lq * 8);
    for (int mt = 0; mt < 4; ++mt)
      for (int nt = 0; nt < 4; ++nt)
        acc[mt][nt] = __builtin_amdgcn_mfma_f32_16x16x32_bf16(af[mt], bfr[nt], acc[mt][nt], 0, 0, 0);
  }

  if (!store_vt) {
    for (int nt = 0; nt < 4; ++nt) {
      int n = blockIdx.x * 128 + wn * 64 + nt * 16 + lr;
      float bvv = bias[n];
      for (int mt = 0; mt < 4; ++mt) {
        size_t mbase = arow0 + wm * 64 + mt * 16 + lq * 4;
        for (int r = 0; r < 4; ++r)
          Cout[(mbase + r) * HD + n] = f2bf(acc[mt][nt][r] + bvv);
      }
    }
  } else {
    for (int nt = 0; nt < 4; ++nt) {
      int n = blockIdx.x * 128 + wn * 64 + nt * 16 + lr;
      float bvv = bias[n];
      int h = n >> 6, d = n & 63;
      for (int mt = 0; mt < 4; ++mt) {
        size_t m0 = arow0 + wm * 64 + mt * 16 + lq * 4;
        size_t bc = m0 >> 8, j = m0 & 255;
        *(ushort4*)(Cout + ((bc * 16 + h) * 64 + d) * 256 + j) =
            make_ushort4(f2bf(acc[mt][nt][0] + bvv), f2bf(acc[mt][nt][1] + bvv),
                         f2bf(acc[mt][nt][2] + bvv), f2bf(acc[mt][nt][3] + bvv));
      }
    }
  }
}

// ---------------- fallback GEMM (fp32 in, register cvt staging) ----------------
__global__ __launch_bounds__(256, 2) void gemm_f32_kernel(
    const float* __restrict__ A, const float* __restrict__ W,
    const float* __restrict__ bias, unsigned short* __restrict__ Cout,
    int store_vt, int qremap) {
  __shared__ unsigned short lds_a[128 * 32];
  __shared__ unsigned short lds_b[128 * 32];
  const int t = threadIdx.x;
  const int l = t & 63, w = t >> 6;
  const int wm = w >> 1, wn = w & 1;
  const int lr = l & 15, lq = l >> 4;
  const size_t arow0 = (size_t)blockIdx.y * 128;
  const size_t brow0 = (size_t)blockIdx.x * 128;

  f32x4 acc[4][4];
  for (int i = 0; i < 4; i++)
    for (int j = 0; j < 4; j++) acc[i][j] = (f32x4){0.f, 0.f, 0.f, 0.f};

  for (int kk = 0; kk < 32; ++kk) {
    const int k0 = kk * 32;
    uint4 av[2], bv[2];
    for (int p = 0; p < 2; ++p) {
      int chunk = p * 256 + t;
      int row = chunk >> 2, c8 = (chunk & 3) * 8;
      size_t grow = arow0 + row;
      bool valid = true;
      const float* srcA;
      if (qremap) {
        int bb = (int)(grow >> 11), tt = (int)(grow & 2047);
        valid = tt < 1985;
        srcA = A + ((size_t)(bb << 11) + tt + 63) * HD + k0 + c8;
      } else {
        srcA = A + grow * HD + k0 + c8;
      }
      if (valid) {
        float4 x = *(const float4*)srcA, y = *(const float4*)(srcA + 4);
        av[p] = make_uint4(pk2bf(x.x, x.y), pk2bf(x.z, x.w), pk2bf(y.x, y.y), pk2bf(y.z, y.w));
      } else av[p] = make_uint4(0, 0, 0, 0);
      const float* srcB = W + (brow0 + row) * HD + k0 + c8;
      float4 x = *(const float4*)srcB, y = *(const float4*)(srcB + 4);
      bv[p] = make_uint4(pk2bf(x.x, x.y), pk2bf(x.z, x.w), pk2bf(y.x, y.y), pk2bf(y.z, y.w));
    }
    __syncthreads();
    for (int p = 0; p < 2; ++p) {
      int chunk = p * 256 + t;
      *(uint4*)(lds_a + chunk * 8) = av[p];
      *(uint4*)(lds_b + chunk * 8) = bv[p];
    }
    __syncthreads();
    bf16x8 af[4], bfr[4];
    for (int mt = 0; mt < 4; ++mt)
      af[mt] = *(const bf16x8*)(lds_a + (wm * 64 + mt * 16 + lr) * 32 + lq * 8);
    for (int nt = 0; nt < 4; ++nt)
      bfr[nt] = *(const bf16x8*)(lds_b + (wn * 64 + nt * 16 + lr) * 32 + lq * 8);
    for (int mt = 0; mt < 4; ++mt)
      for (int nt = 0; nt < 4; ++nt)
        acc[mt][nt] = __builtin_amdgcn_mfma_f32_16x16x32_bf16(af[mt], bfr[nt], acc[mt][nt], 0, 0, 0);
  }

  if (!store_vt) {
    for (int nt = 0; nt < 4; ++nt) {
      int n = blockIdx.x * 128 + wn * 64 + nt * 16 + lr;
      float bvv = bias[n];
      for (int mt = 0; mt < 4; ++mt) {
        size_t mbase = arow0 + wm * 64 + mt * 16 + lq * 4;
        for (int r = 0; r < 4; ++r)
          Cout[(mbase + r) * HD + n] = f2bf(acc[mt][nt][r] + bvv);
      }
    }
  } else {
    for (int nt = 0; nt < 4; ++nt) {
      int n = blockIdx.x * 128 + wn * 64 + nt * 16 + lr;
      float bvv = bias[n];
      int h = n >> 6, d = n & 63;
      for (int mt = 0; mt < 4; ++mt) {
        size_t m0 = arow0 + wm * 64 + mt * 16 + lq * 4;
        size_t bc = m0 >> 8, j = m0 & 255;
        *(ushort4*)(Cout + ((bc * 16 + h) * 64 + d) * 256 + j) =
            make_ushort4(f2bf(acc[mt][nt][0] + bvv), f2bf(acc[mt][nt][1] + bvv),
                         f2bf(acc[mt][nt][2] + bvv), f2bf(acc[mt][nt][3] + bvv));
      }
    }
  }
}

// ---------------- fused attention per (b, c, head); V read direct from Vt ----------------
#define QK_STRIDE 68
#define P_STRIDE 260

__global__ __launch_bounds__(256, 3) void attn_kernel(
    const unsigned short* __restrict__ Qp, const unsigned short* __restrict__ Kp,
    const unsigned short* __restrict__ Vt, float* __restrict__ out) {
  __shared__ unsigned short q_s[64 * QK_STRIDE];    // 8704 B
  __shared__ unsigned short k_s[256 * QK_STRIDE];   // 34816 B; P overlay 64x260 fits
  const int t = threadIdx.x;
  const int l = t & 63, w = t >> 6;
  const int lr = l & 15, lq = l >> 4;
  const int bid = blockIdx.x;
  const int head = bid & 15, cc = (bid >> 4) & 31, b = bid >> 9;
  const size_t qrow0 = (size_t)(b * NC + cc) * 64;
  const size_t kvrow0 = (size_t)(b * NC + cc) * 256;
  const int hcol = head * 64;
  const unsigned short* vbase = Vt + ((size_t)((b * NC + cc) * 16 + head) * 64) * 256;

  for (int p = 0; p < 4; ++p) {
    int chunk = p * 256 + t;
    int row = chunk >> 4, c4 = (chunk & 15) * 4;
    *(uint2*)(q_s + row * QK_STRIDE + c4) = *(const uint2*)(Qp + (qrow0 + row) * HD + hcol + c4);
  }
  for (int p = 0; p < 16; ++p) {
    int chunk = p * 256 + t;
    int row = chunk >> 4, c4 = (chunk & 15) * 4;
    *(uint2*)(k_s + row * QK_STRIDE + c4) = *(const uint2*)(Kp + (kvrow0 + row) * HD + hcol + c4);
  }
  __syncthreads();

  bf16x8 qa0 = ld_frag8(q_s + (w * 16 + lr) * QK_STRIDE + lq * 8);
  bf16x8 qa1 = ld_frag8(q_s + (w * 16 + lr) * QK_STRIDE + 32 + lq * 8);
  f32x4 sc[16];
  for (int nt = 0; nt < 16; ++nt) {
    bf16x8 kb0 = ld_frag8(k_s + (nt * 16 + lr) * QK_STRIDE + lq * 8);
    bf16x8 kb1 = ld_frag8(k_s + (nt * 16 + lr) * QK_STRIDE + 32 + lq * 8);
    f32x4 a = (f32x4){0.f, 0.f, 0.f, 0.f};
    a = __builtin_amdgcn_mfma_f32_16x16x32_bf16(qa0, kb0, a, 0, 0, 0);
    a = __builtin_amdgcn_mfma_f32_16x16x32_bf16(qa1, kb1, a, 0, 0, 0);
    sc[nt] = a;
  }
  float mrow[4] = {-1e30f, -1e30f, -1e30f, -1e30f};
  for (int nt = 0; nt < 16; ++nt)
    for (int r = 0; r < 4; ++r) mrow[r] = fmaxf(mrow[r], sc[nt][r]);
  for (int off = 1; off < 16; off <<= 1)
    for (int r = 0; r < 4; ++r) mrow[r] = fmaxf(mrow[r], __shfl_xor(mrow[r], off, 16));
  float srow[4] = {0.f, 0.f, 0.f, 0.f};
  const float cexp = 0.18033688011112042f;  // log2(e)/8
  for (int nt = 0; nt < 16; ++nt)
    for (int r = 0; r < 4; ++r) {
      float p = exp2f((sc[nt][r] - mrow[r]) * cexp);
      sc[nt][r] = p;
      srow[r] += p;
    }
  for (int off = 1; off < 16; off <<= 1)
    for (int r = 0; r < 4; ++r) srow[r] += __shfl_xor(srow[r], off, 16);

  __syncthreads();  // all waves done reading k_s -> reuse as P

  for (int nt = 0; nt < 16; ++nt)
    for (int r = 0; r < 4; ++r)
      k_s[(w * 16 + lq * 4 + r) * P_STRIDE + nt * 16 + lr] = f2bf(sc[nt][r]);

  f32x4 o[4];
  for (int i = 0; i < 4; ++i) o[i] = (f32x4){0.f, 0.f, 0.f, 0.f};
  for (int ks = 0; ks < 8; ++ks) {
    bf16x8 pa = ld_frag8(k_s + (w * 16 + lr) * P_STRIDE + ks * 32 + lq * 8);
    for (int nt2 = 0; nt2 < 4; ++nt2) {
      bf16x8 vb = *(const bf16x8*)(vbase + (size_t)(nt2 * 16 + lr) * 256 + ks * 32 + lq * 8);
      o[nt2] = __builtin_amdgcn_mfma_f32_16x16x32_bf16(pa, vb, o[nt2], 0, 0, 0);
    }
  }

  for (int r = 0; r < 4; ++r) {
    int strip = w * 16 + lq * 4 + r;
    int trow = cc * 64 + strip;
    if (trow < 1985) {
      size_t orow = (size_t)b * SEQ + trow + 63;
      float inv = 1.0f / srow[r];
      for (int nt2 = 0; nt2 < 4; ++nt2)
        out[orow * HD + hcol + nt2 * 16 + lr] = o[nt2][r] * inv;
    }
  }
}

extern "C" void kernel_launch(void* const* d_in, const int* in_sizes, int n_in,
                              void* d_out, int out_size, void* d_ws, size_t ws_size,
                              hipStream_t stream) {
  (void)in_sizes; (void)n_in; (void)out_size;
  const float* query = (const float*)d_in[0];
  const float* kv    = (const float*)d_in[1];
  const float* Wq    = (const float*)d_in[2];
  const float* bq    = (const float*)d_in[3];
  const float* Wk    = (const float*)d_in[4];
  const float* bk    = (const float*)d_in[5];
  const float* Wv    = (const float*)d_in[6];
  const float* bv    = (const float*)d_in[7];
  float* out = (float*)d_out;

  unsigned short* Qp  = (unsigned short*)d_ws;          // 8192x1024
  unsigned short* Kp  = Qp + (size_t)8192 * 1024;       // 32768x1024
  unsigned short* Vt  = Kp + (size_t)32768 * 1024;      // 32768x1024 (transposed layout)
  unsigned short* Qbf = Vt + (size_t)32768 * 1024;      // 8192x1024
  unsigned short* KVb = Qbf + (size_t)8192 * 1024;      // 32768x1024
  unsigned short* Wqb = KVb + (size_t)32768 * 1024;     // 1024x1024
  unsigned short* Wkb = Wqb + (size_t)1024 * 1024;
  unsigned short* Wvb = Wkb + (size_t)1024 * 1024;
  const size_t need = ((size_t)8192 * 1024 * 2 + (size_t)32768 * 1024 * 2 + (size_t)1024 * 1024 * 3) * 2;
  const bool big = ws_size >= need;

  zero_head_kernel<<<dim3(252), dim3(256), 0, stream>>>(out);
  if (big) {
    cvt_q_kernel<<<dim3(4096), dim3(256), 0, stream>>>(query, Qbf);
    cvt_kernel<<<dim3(16384), dim3(256), 0, stream>>>(kv, KVb, 4194304);
    cvt_kernel<<<dim3(512), dim3(256), 0, stream>>>(Wq, Wqb, 131072);
    cvt_kernel<<<dim3(512), dim3(256), 0, stream>>>(Wk, Wkb, 131072);
    cvt_kernel<<<dim3(512), dim3(256), 0, stream>>>(Wv, Wvb, 131072);
    gemm_bf_kernel<<<dim3(8, 64), dim3(256), 0, stream>>>(Qbf, Wqb, bq, Qp, 0);
    gemm_bf_kernel<<<dim3(8, 256), dim3(256), 0, stream>>>(KVb, Wkb, bk, Kp, 0);
    gemm_bf_kernel<<<dim3(8, 256), dim3(256), 0, stream>>>(KVb, Wvb, bv, Vt, 1);
  } else {
    gemm_f32_kernel<<<dim3(8, 64), dim3(256), 0, stream>>>(query, Wq, bq, Qp, 0, 1);
    gemm_f32_kernel<<<dim3(8, 256), dim3(256), 0, stream>>>(kv, Wk, bk, Kp, 0, 0);
    gemm_f32_kernel<<<dim3(8, 256), dim3(256), 0, stream>>>(kv, Wv, bv, Vt, 1, 0);
  }
  attn_kernel<<<dim3(2048), dim3(256), 0, stream>>>(Qp, Kp, Vt, out);
}